// Round 1
// baseline (267.971 us; speedup 1.0000x reference)
//
#include <hip/hip_runtime.h>
#include <math.h>

#define KN 8
#define EN 16

// mono(x) = exp(-(x*w1 + b1)) . w2 + b2   (E=16, scalar in/out)
__device__ __forceinline__ float mono_eval(float x,
    const float* __restrict__ w1, const float* __restrict__ b1,
    const float* __restrict__ w2, float b2) {
    float acc = 0.0f;
#pragma unroll
    for (int e = 0; e < EN; ++e) {
        float pre = x * w1[e] + b1[e];
        acc += expf(-pre) * w2[e];
    }
    return acc + b2;
}

// angle clamp: keep vec iff |v.vec / max(|v||vec|,1e-8)| > ang ; accumulate
__device__ __forceinline__ void clamp_add(float vx, float vy, float vnorm, float ang,
                                          float fx, float fy, float& ax, float& ay) {
    float num = vx * fx + vy * fy;
    float fn  = sqrtf(fx * fx + fy * fy);
    float den = fmaxf(vnorm * fn, 1e-8f);
    float c   = num / den;
    if (fabsf(c) > ang) { ax += fx; ay += fy; }
}

extern "C" __global__ void __launch_bounds__(256)
sfm_kernel(const float* __restrict__ ego, const float* __restrict__ nei,
           const float* __restrict__ border, const float* __restrict__ rec,
           const float* __restrict__ p_dest, const float* __restrict__ angle,
           const float* __restrict__ rep_w1, const float* __restrict__ rep_b1,
           const float* __restrict__ rep_w2, const float* __restrict__ rep_b2,
           const float* __restrict__ att_w1, const float* __restrict__ att_b1,
           const float* __restrict__ att_w2, const float* __restrict__ att_b2,
           const float* __restrict__ bor_w1, const float* __restrict__ bor_b1,
           const float* __restrict__ bor_w2, const float* __restrict__ bor_b2,
           const float* __restrict__ del_w1, const float* __restrict__ del_b1,
           const float* __restrict__ del_w2, const float* __restrict__ del_b2,
           float* __restrict__ out, int N)
{
    int n = blockIdx.x * blockDim.x + threadIdx.x;
    if (n >= N) return;

    const float ang = angle[0];
    const float p0 = p_dest[0], p1 = p_dest[1];
    const float b0 = border[0], b3 = border[3];

    // ego row: 16 floats, 64B aligned
    const float4* e4 = (const float4*)(ego + (size_t)n * 16);
    float4 ea = e4[0], eb = e4[1], ec = e4[2], ed = e4[3];
    const float px_e = ea.y, py_e = ea.z;   // ego[:,1:3]
    const float vx = ea.w, vy = eb.x;       // ego[:,3:5]
    float egid[8] = {eb.w, ec.x, ec.y, ec.z, ec.w, ed.x, ed.y, ed.z}; // ego[:,7:15]

    const float speed = sqrtf(vx * vx + vy * vy);

    // ---- f_dest + clamp ----
    float fdx = (p1 * speed - vx) / p0;
    float fdy = (0.0f - vy) / p0;           // p1*0 - vy
    float fdestx = 0.0f, fdesty = 0.0f;
    clamp_add(vx, vy, speed, ang, fdx, fdy, fdestx, fdesty);

    // ---- load neighbor fields (only cols 0..4 needed) ----
    const float* nb = nei + (size_t)n * (KN * 16);
    float nid[KN], nx_[KN], ny_[KN], nvx[KN], nvy[KN];
#pragma unroll
    for (int k = 0; k < KN; ++k) {
        float4 a = *(const float4*)(nb + k * 16);
        nid[k] = a.x; nx_[k] = a.y; ny_[k] = a.z; nvx[k] = a.w;
        nvy[k] = nb[k * 16 + 4];
    }

    // ---- recording_time buffer ----
    const float* rbuf = rec + (size_t)n * (KN * 2);
    float bid[KN], bct[KN];
#pragma unroll
    for (int k = 0; k < KN; k += 2) {
        float4 t = *(const float4*)(rbuf + k * 2);
        bid[k] = t.x; bct[k] = t.y; bid[k + 1] = t.z; bct[k + 1] = t.w;
    }

    // ---- count logic: stable priority fill emulating the argsort-select ----
    float cnt[KN];
#pragma unroll
    for (int k = 0; k < KN; ++k) cnt[k] = 1.0f;   // fill value of new_buf
    int slot = 0;
#pragma unroll
    for (int k = 0; k < KN; ++k) {                // ifin: buf entries seen again
        bool fin = false;
#pragma unroll
        for (int j = 0; j < KN; ++j) fin |= (bid[k] == nid[j]);
        if (fin) {
            float v2 = bct[k] + 1.0f;             // ct2 = buf_ct + ifin
#pragma unroll
            for (int s = 0; s < KN; ++s) if (slot == s) cnt[s] = v2;
            slot++;
        }
    }
#pragma unroll
    for (int k = 0; k < KN; ++k) {                // ifnew: fresh neighbor ids
        bool inbuf = false;
#pragma unroll
        for (int j = 0; j < KN; ++j) inbuf |= (nid[k] == bid[j]);
        bool isnew = (!inbuf) && (nid[k] != 0.0f);
        if (isnew) {
#pragma unroll
            for (int s = 0; s < KN; ++s) if (slot == s) cnt[s] = 1.0f;
            slot++;
        }
    }

    const float del_one = mono_eval(1.0f, del_w1, del_b1, del_w2, del_b2[0]);

    // ---- neighbor forces ----
    float fax_acc = 0.0f, fay_acc = 0.0f;   // attr
    float frx_acc = 0.0f, fry_acc = 0.0f;   // repu
#pragma unroll
    for (int k = 0; k < KN; ++k) {
        bool match = false;
#pragma unroll
        for (int j = 0; j < 8; ++j) match |= (nid[k] == egid[j]);
        const bool idxk = match && (nid[k] != 0.0f);

        float rx = idxk ? (nx_[k] - px_e) : 0.0f;
        float ry = idxk ? (ny_[k] - py_e) : 0.0f;
        float rn = sqrtf(rx * rx + ry * ry);
        float rns = idxk ? rn : 1.0f;
        float dx = rx / rns, dy = ry / rns;

        float att = mono_eval(rn, att_w1, att_b1, att_w2, att_b2[0]);
        float del = (cnt[k] == 1.0f) ? del_one
                  : mono_eval(cnt[k], del_w1, del_b1, del_w2, del_b2[0]);
        float fax = del * att * dx;
        float fay = del * att * dy;
        if (!idxk) { fax = 0.0f; fay = 0.0f; }
        clamp_add(vx, vy, speed, ang, fax, fay, fax_acc, fay_acc);

        float sx = nvx[k] * 0.02f, sy = nvy[k] * 0.02f;
        float ox = rx + sx, oy = ry + sy;
        float bsum = rn + (ox * ox + oy * oy) - (sx * sx + sy * sy);
        float bgate = idxk ? bsum : 1.0f;
        float bb = sqrtf(fmaxf(bgate, 1e-12f)) / 2.0f;

        float rep = mono_eval(bb, rep_w1, rep_b1, rep_w2, rep_b2[0]);
        float frx = rep * dx, fry = rep * dy;
        if (!idxk) { frx = 0.0f; fry = 0.0f; }
        clamp_add(vx, vy, speed, ang, frx, fry, frx_acc, fry_acc);
    }

    // ---- border forces: uses border[0] and border[3], y-component only ----
    float fbx_acc = 0.0f, fby_acc = 0.0f;
    float rbv0 = py_e - b0, rbv1 = py_e - b3;
#pragma unroll
    for (int r = 0; r < 2; ++r) {
        float rb = (r == 0) ? rbv0 : rbv1;
        float rbn = fabsf(rb);
        float m = mono_eval(rbn, bor_w1, bor_b1, bor_w2, bor_b2[0]);
        float fby = m * (rb / rbn);
        clamp_add(vx, vy, speed, ang, 0.0f, fby, fbx_acc, fby_acc);
    }

    // ---- output (N,3,2) ----
    float2* o = (float2*)(out + (size_t)n * 6);
    o[0] = make_float2(fdestx, fdesty);
    o[1] = make_float2(fax_acc + frx_acc, fay_acc + fry_acc);
    o[2] = make_float2(fbx_acc, fby_acc);
}

extern "C" void kernel_launch(void* const* d_in, const int* in_sizes, int n_in,
                              void* d_out, int out_size, void* d_ws, size_t ws_size,
                              hipStream_t stream) {
    const float* ego    = (const float*)d_in[0];
    const float* nei    = (const float*)d_in[1];
    const float* border = (const float*)d_in[2];
    const float* rec    = (const float*)d_in[3];
    const float* p_dest = (const float*)d_in[4];
    const float* angle  = (const float*)d_in[5];
    const float* rep_w1 = (const float*)d_in[6];
    const float* rep_b1 = (const float*)d_in[7];
    const float* rep_w2 = (const float*)d_in[8];
    const float* rep_b2 = (const float*)d_in[9];
    const float* att_w1 = (const float*)d_in[10];
    const float* att_b1 = (const float*)d_in[11];
    const float* att_w2 = (const float*)d_in[12];
    const float* att_b2 = (const float*)d_in[13];
    const float* bor_w1 = (const float*)d_in[14];
    const float* bor_b1 = (const float*)d_in[15];
    const float* bor_w2 = (const float*)d_in[16];
    const float* bor_b2 = (const float*)d_in[17];
    const float* del_w1 = (const float*)d_in[18];
    const float* del_b1 = (const float*)d_in[19];
    const float* del_w2 = (const float*)d_in[20];
    const float* del_b2 = (const float*)d_in[21];
    float* out = (float*)d_out;

    int N = in_sizes[0] / 16;
    dim3 grid((N + 255) / 256);
    sfm_kernel<<<grid, 256, 0, stream>>>(
        ego, nei, border, rec, p_dest, angle,
        rep_w1, rep_b1, rep_w2, rep_b2,
        att_w1, att_b1, att_w2, att_b2,
        bor_w1, bor_b1, bor_w2, bor_b2,
        del_w1, del_b1, del_w2, del_b2,
        out, N);
}

// Round 2
// 251.464 us; speedup vs baseline: 1.0656x; 1.0656x over previous
//
#include <hip/hip_runtime.h>
#include <math.h>

#define EN 16

// mono(x) = exp(-(x*w1 + b1)) . w2 + b2  — fast native exp.
// Gate-safety: angle gates depend only on force *direction*, never on mono
// magnitudes, so __expf's ~1ulp deviation cannot flip a gate.
__device__ __forceinline__ float mono_fast(float x,
    const float* __restrict__ w1, const float* __restrict__ b1,
    const float* __restrict__ w2, const float* __restrict__ b2) {
    float acc = 0.0f;
#pragma unroll
    for (int e = 0; e < EN; ++e) {
        float pre = fmaf(x, w1[e], b1[e]);
        acc = fmaf(__expf(-pre), w2[e], acc);
    }
    return acc + b2[0];
}

// One lane per (agent n, neighbor k): 8 lanes per agent within a wave.
extern "C" __global__ void __launch_bounds__(256)
sfm_kernel(const float* __restrict__ ego, const float* __restrict__ nei,
           const float* __restrict__ border, const float* __restrict__ rec,
           const float* __restrict__ p_dest, const float* __restrict__ angle,
           const float* __restrict__ rep_w1, const float* __restrict__ rep_b1,
           const float* __restrict__ rep_w2, const float* __restrict__ rep_b2,
           const float* __restrict__ att_w1, const float* __restrict__ att_b1,
           const float* __restrict__ att_w2, const float* __restrict__ att_b2,
           const float* __restrict__ bor_w1, const float* __restrict__ bor_b1,
           const float* __restrict__ bor_w2, const float* __restrict__ bor_b2,
           const float* __restrict__ del_w1, const float* __restrict__ del_b1,
           const float* __restrict__ del_w2, const float* __restrict__ del_b2,
           float* __restrict__ out, int N)
{
    const int gid = blockIdx.x * blockDim.x + threadIdx.x;
    const int n = gid >> 3;
    const int k = gid & 7;
    if (n >= N) return;
    const int lane = threadIdx.x & 63;
    const int gbase = lane & ~7;   // first lane of this agent's 8-lane group

    const float ang = angle[0];
    const float p0 = p_dest[0], p1 = p_dest[1];

    // ego row (broadcast within group: all 8 lanes same address)
    const float* er = ego + (size_t)n * 16;
    float4 ea = *(const float4*)(er);       // cols 0..3
    float4 eb = *(const float4*)(er + 4);   // cols 4..7
    float4 ec = *(const float4*)(er + 8);   // cols 8..11
    float4 ed = *(const float4*)(er + 12);  // cols 12..15
    const float px = ea.y, py = ea.z, vx = ea.w, vy = eb.x;
    const float speed = sqrtf(vx * vx + vy * vy);

    // neighbor row for (n,k): lane-consecutive 64B stride -> coalesced
    const float* nb = nei + (size_t)n * 128 + (size_t)k * 16;
    float4 na = *(const float4*)nb;          // id, x, y, vx
    const float nvyv = nb[4];                // vy
    const float nid = na.x;

    // recording buffer entry (n,k): 8B/lane consecutive
    float2 rc = *(const float2*)(rec + (size_t)n * 16 + (size_t)k * 2);
    const float bid = rc.x, bct = rc.y;

    // ifin[k] = buf_id[k] present among this agent's nei ids (all-pairs via xor shuffles)
    bool fin = (bid == nid);
#pragma unroll
    for (int t = 1; t < 8; ++t)
        fin = fin || (bid == __shfl_xor(nid, t));

    // count for slot k of the argsort-select:
    //   first popc(fin) slots take (bct[j-th fin]+1) in j order; rest are 1.0
    //   (new entries and the fill value are both 1.0 -> ifnew is dead code)
    unsigned long long bal = __ballot(fin);
    unsigned finM = (unsigned)((bal >> gbase) & 0xFFull);
    int popcFin = __popc(finM);
    int jsel = 0, cbits = 0;
#pragma unroll
    for (int j = 0; j < 8; ++j) {
        int bit = (finM >> j) & 1;
        if (bit && cbits == k) jsel = j;
        cbits += bit;
    }
    float bctj = __shfl(bct, gbase + jsel);
    float cntk = (k < popcFin) ? (bctj + 1.0f) : 1.0f;

    // idx: neighbor id among ego[:,7:15]
    bool match = (nid == eb.w) || (nid == ec.x) || (nid == ec.y) || (nid == ec.z)
              || (nid == ec.w) || (nid == ed.x) || (nid == ed.y) || (nid == ed.z);
    const bool idxk = match && (nid != 0.0f);

    float rx = idxk ? (na.y - px) : 0.0f;
    float ry = idxk ? (na.z - py) : 0.0f;
    float rn = sqrtf(rx * rx + ry * ry);
    float rns = idxk ? rn : 1.0f;
    float dx = rx / rns, dy = ry / rns;

    // attraction = mono_del(count) * mono_att(rn) * dir
    float att = mono_fast(rn,   att_w1, att_b1, att_w2, att_b2);
    float del = mono_fast(cntk, del_w1, del_b1, del_w2, del_b2);
    float sa = del * att;
    float fax = idxk ? sa * dx : 0.0f;
    float fay = idxk ? sa * dy : 0.0f;

    float nbx = 0.0f, nby = 0.0f;
    {
        float num = vx * fax + vy * fay;
        float fn = sqrtf(fax * fax + fay * fay);
        float den = fmaxf(speed * fn, 1e-8f);
        if (fabsf(num / den) > ang) { nbx += fax; nby += fay; }
    }

    // repulsion
    float sxv = na.w * 0.02f, syv = nvyv * 0.02f;
    float ox = rx + sxv, oy = ry + syv;
    float bsum = rn + (ox * ox + oy * oy) - (sxv * sxv + syv * syv);
    float bgate = idxk ? bsum : 1.0f;
    float bb = sqrtf(fmaxf(bgate, 1e-12f)) * 0.5f;
    float rep = mono_fast(bb, rep_w1, rep_b1, rep_w2, rep_b2);
    float frx = idxk ? rep * dx : 0.0f;
    float fry = idxk ? rep * dy : 0.0f;
    {
        float num = vx * frx + vy * fry;
        float fn = sqrtf(frx * frx + fry * fry);
        float den = fmaxf(speed * fn, 1e-8f);
        if (fabsf(num / den) > ang) { nbx += frx; nby += fry; }
    }

    // border force: y-only; lanes k==0 (border[0]) and k==1 (border[3]) contribute
    float bsel = (k == 0) ? border[0] : border[3];
    float rb = py - bsel;
    float rbn = fabsf(rb);
    float mb = mono_fast(rbn, bor_w1, bor_b1, bor_w2, bor_b2);
    float fby = mb * (rb / rbn);
    float bory = 0.0f;
    {
        float num = vy * fby;
        float den = fmaxf(speed * fabsf(fby), 1e-8f);
        if ((fabsf(num / den) > ang) && (k < 2)) bory = fby;
    }

    // xor-butterfly reduce over the 8-lane group (all lanes end with the sum)
#pragma unroll
    for (int m = 1; m < 8; m <<= 1) {
        nbx  += __shfl_xor(nbx,  m);
        nby  += __shfl_xor(nby,  m);
        bory += __shfl_xor(bory, m);
    }

    // destination force (uniform across group, cheap: compute everywhere)
    float fdx = (p1 * speed - vx) / p0;
    float fdy = (0.0f - vy) / p0;
    float fdex = 0.0f, fdey = 0.0f;
    {
        float num = vx * fdx + vy * fdy;
        float fn = sqrtf(fdx * fdx + fdy * fdy);
        float den = fmaxf(speed * fn, 1e-8f);
        if (fabsf(num / den) > ang) { fdex = fdx; fdey = fdy; }
    }

    // output (N,3,2): lanes 0..5 each write one float (coalesced-ish)
    float wv = (k == 0) ? fdex
             : (k == 1) ? fdey
             : (k == 2) ? nbx
             : (k == 3) ? nby
             : (k == 4) ? 0.0f
             : bory;
    if (k < 6) out[(size_t)n * 6 + k] = wv;
}

extern "C" void kernel_launch(void* const* d_in, const int* in_sizes, int n_in,
                              void* d_out, int out_size, void* d_ws, size_t ws_size,
                              hipStream_t stream) {
    const float* ego    = (const float*)d_in[0];
    const float* nei    = (const float*)d_in[1];
    const float* border = (const float*)d_in[2];
    const float* rec    = (const float*)d_in[3];
    const float* p_dest = (const float*)d_in[4];
    const float* angle  = (const float*)d_in[5];
    const float* rep_w1 = (const float*)d_in[6];
    const float* rep_b1 = (const float*)d_in[7];
    const float* rep_w2 = (const float*)d_in[8];
    const float* rep_b2 = (const float*)d_in[9];
    const float* att_w1 = (const float*)d_in[10];
    const float* att_b1 = (const float*)d_in[11];
    const float* att_w2 = (const float*)d_in[12];
    const float* att_b2 = (const float*)d_in[13];
    const float* bor_w1 = (const float*)d_in[14];
    const float* bor_b1 = (const float*)d_in[15];
    const float* bor_w2 = (const float*)d_in[16];
    const float* bor_b2 = (const float*)d_in[17];
    const float* del_w1 = (const float*)d_in[18];
    const float* del_b1 = (const float*)d_in[19];
    const float* del_w2 = (const float*)d_in[20];
    const float* del_b2 = (const float*)d_in[21];
    float* out = (float*)d_out;

    int N = in_sizes[0] / 16;
    long long threads = (long long)N * 8;
    dim3 grid((unsigned)((threads + 255) / 256));
    sfm_kernel<<<grid, 256, 0, stream>>>(
        ego, nei, border, rec, p_dest, angle,
        rep_w1, rep_b1, rep_w2, rep_b2,
        att_w1, att_b1, att_w2, att_b2,
        bor_w1, bor_b1, bor_w2, bor_b2,
        del_w1, del_b1, del_w2, del_b2,
        out, N);
}